// Round 6
// baseline (244.180 us; speedup 1.0000x reference)
//
#include <hip/hip_runtime.h>

// ONINorm: g=16 groups, n=128 rows/group, d=9216 cols, T=5 Newton-Schulz iters.
// v10 = v5 (187.7us baseline) with two changes:
//   k_sgemm: double-buffered LDS (2x32KB), ONE barrier per step instead of two.
//            Per step: prefetch(s+1) -> MFMA(tile[s&1]) -> convert(s+1) into
//            tile[(s+1)&1] -> barrier. Passing barrier(s) proves all waves did
//            MFMA(s-1) (last reader of the buffer convert(s+1) overwrites), so
//            the structure is race-free. Halves the vmcnt(0) barrier drains.
//   k_reduce fused into k_ns: each group block sums its 16 Spart panels (L3-
//            hot), applies rank-1 mu correction + eps, computes fro-norm in-
//            block (S staged f32 in the Ub/Vt LDS region, dead until iter 1),
//            writes gnorm[g] for k_wgemm. One fewer dispatch + no Sred trip.
// k_ns (512 thr) and k_wgemm (Ab staged in LDS) otherwise v5-verbatim (the v9
// variants regressed ~7us net and are reverted).
//   S = Z*Z^T - d*mu*mu^T ; W = (B5*Z)*ss - (B5*mu)*ss*1^T

#define G 16
#define NROW 128
#define D 9216
#define OC 2048
#define KSPLIT 16
#define KCHUNK 576   // D / KSPLIT = 4*128 + 64
#define EPSV 1e-5f

typedef float f32x16 __attribute__((ext_vector_type(16)));
typedef __bf16 bf16x8 __attribute__((ext_vector_type(8)));

union Frag {
    uint4 q;
    unsigned short s[8];
    bf16x8 v;
};

static __device__ __forceinline__ unsigned short f2bf(float x) {
    union { float f; unsigned int u; } a; a.f = x;
    unsigned int u = a.u;
    unsigned int r = u + 0x7FFFu + ((u >> 16) & 1u);   // RNE, inputs are finite
    return (unsigned short)(r >> 16);
}

static __device__ __forceinline__ float bf2f(unsigned short s) {
    union { unsigned int u; float f; } a; a.u = ((unsigned int)s) << 16;
    return a.f;
}

// Swizzled 128x128 bf16 tile layout. Granule = 8 elems = 16B.
// addr(r,c) = r*128 + ((c/8) ^ (r&15))*8 + c%8
static __device__ __forceinline__ int swz(int r, int c) {
    return (r << 7) + ((((c >> 3) ^ (r & 15)) << 3) | (c & 7));
}

// --------------- K1: G partials from raw W + Zraw bf16 byproduct + rowsums ----
// Double-buffered, one barrier per step. 256 thr, grid 256 (1 block/CU).
__global__ __launch_bounds__(256, 1) void k_sgemm(const float* __restrict__ W,
                                                  unsigned short* __restrict__ Zraw,
                                                  float* __restrict__ Spart,
                                                  float* __restrict__ rowsumPart) {
    __shared__ unsigned short tile[2][NROW * 128];
    __shared__ float rsum[NROW];
    int bid = blockIdx.x;
    int g = bid >> 4, ks = bid & 15;
    int t = threadIdx.x, lane = t & 63, wave = t >> 6;
    int mq = (wave & 1) * 64, nq = (wave >> 1) * 64;
    int m = lane & 31, h = lane >> 5;

    if (t < 128) rsum[t] = 0.f;

    f32x16 acc[2][2];
#pragma unroll
    for (int i = 0; i < 2; i++)
#pragma unroll
        for (int j = 0; j < 2; j++)
#pragma unroll
            for (int z = 0; z < 16; z++) acc[i][j][z] = 0.f;

    float rs[16], rsh[8];
#pragma unroll
    for (int i = 0; i < 16; i++) rs[i] = 0.f;
#pragma unroll
    for (int i = 0; i < 8; i++) rsh[i] = 0.f;

    const float* wg = W + (size_t)g * NROW * D + ks * KCHUNK;
    unsigned short* zo = Zraw + (size_t)g * NROW * D + ks * KCHUNK;

    float4 pf[16];
#pragma unroll
    for (int p = 0; p < 16; p++) {                 // preload step 0
        int fl = p * 256 + t, r = fl >> 5, cf = fl & 31;
        pf[p] = *(const float4*)(wg + (size_t)r * D + cf * 4);
    }
    {   // convert step 0 -> tile[0]
#pragma unroll
        for (int p = 0; p < 16; p++) {
            int fl = p * 256 + t, r = fl >> 5, cf = fl & 31;
            float4 x = pf[p];
            rs[p] += x.x + x.y + x.z + x.w;
            ushort4 pk;
            pk.x = f2bf(x.x); pk.y = f2bf(x.y);
            pk.z = f2bf(x.z); pk.w = f2bf(x.w);
            *(ushort4*)(zo + (size_t)r * D + cf * 4) = pk;
            union { ushort4 s4; uint2 u; } cv; cv.s4 = pk;
            *(uint2*)(tile[0] + swz(r, cf * 4)) = cv.u;
        }
    }
    __syncthreads();

#pragma unroll
    for (int s = 0; s < 5; s++) {
        // ---- prefetch step s+1 (loads in flight during MFMA) ----
        if (s < 3) {
            int dbase = (s + 1) * 128;
#pragma unroll
            for (int p = 0; p < 16; p++) {
                int fl = p * 256 + t, r = fl >> 5, cf = fl & 31;
                pf[p] = *(const float4*)(wg + (size_t)r * D + dbase + cf * 4);
            }
        } else if (s == 3) {
#pragma unroll
            for (int p = 0; p < 8; p++) {
                int fl = p * 256 + t, r = fl >> 4, cf = fl & 15;
                pf[p] = *(const float4*)(wg + (size_t)r * D + 512 + cf * 4);
            }
        }
        // ---- MFMA on tile[s&1] ----
        const unsigned short* tl = tile[s & 1];
        int kmax = (s < 4) ? 8 : 4;
#pragma unroll
        for (int kk = 0; kk < 8; kk++) {
            if (kk >= kmax) break;
            int kb = kk * 16 + h * 8;
            Frag a0, a1, b0, b1;
            a0.q = *(const uint4*)(tl + swz(mq + m, kb));
            a1.q = *(const uint4*)(tl + swz(mq + 32 + m, kb));
            b0.q = *(const uint4*)(tl + swz(nq + m, kb));
            b1.q = *(const uint4*)(tl + swz(nq + 32 + m, kb));
            acc[0][0] = __builtin_amdgcn_mfma_f32_32x32x16_bf16(a0.v, b0.v, acc[0][0], 0, 0, 0);
            acc[0][1] = __builtin_amdgcn_mfma_f32_32x32x16_bf16(a0.v, b1.v, acc[0][1], 0, 0, 0);
            acc[1][0] = __builtin_amdgcn_mfma_f32_32x32x16_bf16(a1.v, b0.v, acc[1][0], 0, 0, 0);
            acc[1][1] = __builtin_amdgcn_mfma_f32_32x32x16_bf16(a1.v, b1.v, acc[1][1], 0, 0, 0);
        }
        // ---- convert step s+1 into the other buffer ----
        if (s < 3) {
            int dbase = (s + 1) * 128;
            unsigned short* td = tile[(s + 1) & 1];
#pragma unroll
            for (int p = 0; p < 16; p++) {
                int fl = p * 256 + t, r = fl >> 5, cf = fl & 31;
                float4 x = pf[p];
                rs[p] += x.x + x.y + x.z + x.w;
                ushort4 pk;
                pk.x = f2bf(x.x); pk.y = f2bf(x.y);
                pk.z = f2bf(x.z); pk.w = f2bf(x.w);
                *(ushort4*)(zo + (size_t)r * D + dbase + cf * 4) = pk;
                union { ushort4 s4; uint2 u; } cv; cv.s4 = pk;
                *(uint2*)(td + swz(r, cf * 4)) = cv.u;
            }
        } else if (s == 3) {
            unsigned short* td = tile[0];
#pragma unroll
            for (int p = 0; p < 8; p++) {
                int fl = p * 256 + t, r = fl >> 4, cf = fl & 15;
                float4 x = pf[p];
                rsh[p] += x.x + x.y + x.z + x.w;
                ushort4 pk;
                pk.x = f2bf(x.x); pk.y = f2bf(x.y);
                pk.z = f2bf(x.z); pk.w = f2bf(x.w);
                *(ushort4*)(zo + (size_t)r * D + 512 + cf * 4) = pk;
                union { ushort4 s4; uint2 u; } cv; cv.s4 = pk;
                *(uint2*)(td + swz(r, cf * 4)) = cv.u;
            }
        }
        if (s < 4) __syncthreads();
    }
    float* sp = Spart + (size_t)bid * 16384;
#pragma unroll
    for (int i = 0; i < 2; i++)
#pragma unroll
        for (int j = 0; j < 2; j++)
#pragma unroll
            for (int reg = 0; reg < 16; reg++) {
                int row = (reg & 3) + 8 * (reg >> 2) + 4 * h;
                sp[(mq + i * 32 + row) * 128 + nq + j * 32 + m] = acc[i][j][reg];
            }
    // fold per-thread rowsums into LDS, then one global write
#pragma unroll
    for (int p = 0; p < 16; p++) atomicAdd(&rsum[p * 8 + (t >> 5)], rs[p]);
#pragma unroll
    for (int p = 0; p < 8; p++) atomicAdd(&rsum[p * 16 + (t >> 4)], rsh[p]);
    __syncthreads();
    if (t < 128) rowsumPart[bid * 128 + t] = rsum[t];
}

// ----- K3: fused reduce + Newton-Schulz (one blk/group, 512 thr) + c = B5*mu --
// Front: sum 16 Spart panels -> S f32 in LDS (Sf overlays Ub/Vt), rank-1 mu
// correction + eps, fro-norm in-block -> gnorm[g]. Then v5 NS iterations.
__global__ __launch_bounds__(512) void k_ns(const float* __restrict__ Spart,
                                            const float* __restrict__ rowsumPart,
                                            unsigned short* __restrict__ Bt,
                                            float* __restrict__ cvec,
                                            float* __restrict__ gnorm) {
    extern __shared__ unsigned short sm[];
    unsigned short* Bb = sm;
    unsigned short* Sb = sm + 16384;
    unsigned short* Ub = sm + 32768;
    unsigned short* Vt = sm + 49152;
    float* Sf = (float*)(sm + 32768);     // 64KB f32 S, overlays Ub+Vt (dead until iters)
    float* muv0 = (float*)sm;             // overlays Bb, dead before init writes Bb
    float* red = ((float*)sm) + 128;      // 8 wave partials, also in Bb region
    int g = blockIdx.x;
    int t = threadIdx.x, lane = t & 63, wave = t >> 6;
    int m = lane & 31, h = lane >> 5;

    if (t < 128) {
        float s = 0.f;
        for (int ks = 0; ks < KSPLIT; ks++) s += rowsumPart[(g * 16 + ks) * 128 + t];
        muv0[t] = s * (1.0f / 9216.0f);
    }
    __syncthreads();

    // reduce partials + correction + eps + per-thread norm partial
    const float* sp0 = Spart + (size_t)g * KSPLIT * 16384;
    float sq = 0.f;
#pragma unroll
    for (int q2 = 0; q2 < 8; q2++) {
        int el = t * 32 + q2 * 4;
        float4 s = {0.f, 0.f, 0.f, 0.f};
        for (int ks = 0; ks < KSPLIT; ks++) {
            float4 p = *(const float4*)(sp0 + (size_t)ks * 16384 + el);
            s.x += p.x; s.y += p.y; s.z += p.z; s.w += p.w;
        }
        int r = el >> 7, c = el & 127;
        float dm = 9216.0f * muv0[r];
        s.x -= dm * muv0[c];     s.y -= dm * muv0[c + 1];
        s.z -= dm * muv0[c + 2]; s.w -= dm * muv0[c + 3];
        if (r >= c && r <= c + 3) {
            if (r == c) s.x += EPSV;
            else if (r == c + 1) s.y += EPSV;
            else if (r == c + 2) s.z += EPSV;
            else s.w += EPSV;
        }
        *(float4*)(Sf + el) = s;
        sq += s.x * s.x + s.y * s.y + s.z * s.z + s.w * s.w;
    }
#pragma unroll
    for (int o = 32; o > 0; o >>= 1) sq += __shfl_down(sq, o, 64);
    if (lane == 0) red[wave] = sq;
    __syncthreads();
    float ns = red[0] + red[1] + red[2] + red[3] + red[4] + red[5] + red[6] + red[7];
    if (t == 0) gnorm[g] = ns;
    float rn = 1.0f / sqrtf(ns);
    __syncthreads();   // all reads of red/muv0 done before Bb/Sb writes below

    {   // init Sn (bf16) and B1 = 1.5I - 0.5*Sn from LDS Sf (each thread 1/4 row)
        int r = t >> 2, c0 = (t & 3) * 32;
        const float* sp = Sf + r * 128 + c0;
#pragma unroll
        for (int q = 0; q < 4; q++) {
            int c = c0 + q * 8;
            float4 x0 = *(const float4*)(sp + q * 8);
            float4 x1 = *(const float4*)(sp + q * 8 + 4);
            float vv[8] = {x0.x, x0.y, x0.z, x0.w, x1.x, x1.y, x1.z, x1.w};
            Frag fs, fb;
#pragma unroll
            for (int i = 0; i < 8; i++) {
                float sv = vv[i] * rn;
                fs.s[i] = f2bf(sv);
                float bv = -0.5f * sv + ((r == c + i) ? 1.5f : 0.f);
                fb.s[i] = f2bf(bv);
            }
            *(uint4*)(Sb + swz(r, c)) = fs.q;
            *(uint4*)(Bb + swz(r, c)) = fb.q;
        }
    }
    Frag fI[2];   // 1.5*I A-fragments
#pragma unroll
    for (int kk2 = 0; kk2 < 2; kk2++)
#pragma unroll
        for (int j = 0; j < 8; j++)
            fI[kk2].s[j] = (m == kk2 * 16 + h * 8 + j) ? (unsigned short)0x3FC0
                                                       : (unsigned short)0;
    __syncthreads();

    for (int iter = 0; iter < 4; iter++) {
        // phase1: 32 tile-tasks (16 U=B*B^T + 16 V=(-0.5 B*S)^T) over 8 waves
#pragma unroll
        for (int i = 0; i < 4; i++) {
            int task = wave * 4 + i;
            int tmb = ((task >> 2) & 3) * 32, tnb = (task & 3) * 32;
            const unsigned short* Bsrc = (task < 16) ? Bb : Sb;
            unsigned short* dst = (task < 16) ? Ub : Vt;
            float sc = (task < 16) ? 1.0f : -0.5f;
            f32x16 acc;
#pragma unroll
            for (int z = 0; z < 16; z++) acc[z] = 0.f;
#pragma unroll
            for (int kk = 0; kk < 8; kk++) {
                Frag a, bfr;
                a.q = *(const uint4*)(Bb + swz(tmb + m, kk * 16 + h * 8));
                bfr.q = *(const uint4*)(Bsrc + swz(tnb + m, kk * 16 + h * 8));
                acc = __builtin_amdgcn_mfma_f32_32x32x16_bf16(a.v, bfr.v, acc, 0, 0, 0);
            }
#pragma unroll
            for (int q = 0; q < 4; q++) {
                union { unsigned short s[4]; uint2 u; } pk;
#pragma unroll
                for (int j = 0; j < 4; j++) pk.s[j] = f2bf(sc * acc[q * 4 + j]);
                *(uint2*)(dst + swz(tnb + m, tmb + q * 8 + h * 4)) = pk.u;
            }
        }
        __syncthreads();
        // phase2: Bnew = U*V' + 1.5I*B in registers
        f32x16 acc2[2];
#pragma unroll
        for (int i = 0; i < 2; i++) {
            int task = wave * 2 + i;
            int tmb = (task >> 2) * 32, tnb = (task & 3) * 32;
#pragma unroll
            for (int z = 0; z < 16; z++) acc2[i][z] = 0.f;
#pragma unroll
            for (int kk = 0; kk < 8; kk++) {
                Frag a, bfr;
                a.q = *(const uint4*)(Ub + swz(tmb + m, kk * 16 + h * 8));
                bfr.q = *(const uint4*)(Vt + swz(tnb + m, kk * 16 + h * 8));
                acc2[i] = __builtin_amdgcn_mfma_f32_32x32x16_bf16(a.v, bfr.v, acc2[i], 0, 0, 0);
            }
#pragma unroll
            for (int kk2 = 0; kk2 < 2; kk2++) {
                Frag bfr;
                bfr.q = *(const uint4*)(Bb + swz(tnb + m, tmb + kk2 * 16 + h * 8));
                acc2[i] = __builtin_amdgcn_mfma_f32_32x32x16_bf16(fI[kk2].v, bfr.v, acc2[i], 0, 0, 0);
            }
        }
        __syncthreads();
#pragma unroll
        for (int i = 0; i < 2; i++) {
            int task = wave * 2 + i;
            int tmb = (task >> 2) * 32, tnb = (task & 3) * 32;
#pragma unroll
            for (int q = 0; q < 4; q++) {
                union { unsigned short s[4]; uint2 u; } pk;
#pragma unroll
                for (int j = 0; j < 4; j++) pk.s[j] = f2bf(acc2[i][q * 4 + j]);
                *(uint2*)(Bb + swz(tnb + m, tmb + q * 8 + h * 4)) = pk.u;
            }
        }
        __syncthreads();
    }
    {   // write B5 row-major bf16 to global
        int r = t >> 2, c0 = (t & 3) * 32;
        unsigned short* bp = Bt + (size_t)g * 16384 + r * 128;
#pragma unroll
        for (int q = 0; q < 4; q++) {
            uint4 dd = *(const uint4*)(Bb + swz(r, c0 + q * 8));
            *(uint4*)(bp + c0 + q * 8) = dd;
        }
    }
    // c = B5 * mu  (mu recomputed; overlays the now-free Ub region)
    float* muv = (float*)(sm + 32768);
    if (t < 128) {
        float s = 0.f;
        for (int ks = 0; ks < KSPLIT; ks++) s += rowsumPart[(g * 16 + ks) * 128 + t];
        muv[t] = s * (1.0f / 9216.0f);
    }
    __syncthreads();
    if (t < 128) {
        float cacc = 0.f;
        for (int k = 0; k < 128; k++) cacc += bf2f(Bb[swz(t, k)]) * muv[k];
        cvec[g * 128 + t] = cacc;
    }
}

// --------------- K4: out = (B5 * Zraw)*ss - (B5*mu)*ss, row-broadcast ---------
// (v5-verbatim except ss comes from the per-group scalar gnorm[g])
__global__ __launch_bounds__(256) void k_wgemm(const unsigned short* __restrict__ Zraw,
                                               const unsigned short* __restrict__ Bt,
                                               const float* __restrict__ gnorm,
                                               const float* __restrict__ cvec,
                                               float* __restrict__ out) {
    __shared__ unsigned short Ab[16384];   // B5 tile, swizzled [row][k]
    __shared__ unsigned short Zt[16384];   // Zraw slice, swizzled [k][col]
    __shared__ float cs[128];
    int nt = blockIdx.x, g = blockIdx.y;
    int t = threadIdx.x, lane = t & 63, wave = t >> 6;
    int m = lane & 31, h = lane >> 5;

    float ss = 1.0f / sqrtf(sqrtf(gnorm[g]));   // 1/sqrt(norm_S)

    const unsigned short* bg = Bt + (size_t)g * 16384;
    const unsigned short* zg = Zraw + (size_t)g * NROW * D + nt * 128;
#pragma unroll
    for (int p = 0; p < 8; p++) {
        int flat = p * 256 + t;
        int r = flat >> 4, gc = flat & 15;
        uint4 da = *(const uint4*)(bg + r * 128 + gc * 8);
        uint4 dz = *(const uint4*)(zg + (size_t)r * D + gc * 8);
        *(uint4*)(Ab + swz(r, gc * 8)) = da;
        *(uint4*)(Zt + swz(r, gc * 8)) = dz;
    }
    if (t < 128) cs[t] = cvec[g * 128 + t] * ss;
    __syncthreads();

    int cw = wave * 32 + m;                  // this lane's output column (in tile)

    f32x16 acc[4];
#pragma unroll
    for (int i = 0; i < 4; i++)
#pragma unroll
        for (int z = 0; z < 16; z++) acc[i][z] = 0.f;

#pragma unroll
    for (int ks = 0; ks < 8; ks++) {
        int k0 = ks * 16 + h * 8;
        Frag b;
#pragma unroll
        for (int j = 0; j < 8; j++) b.s[j] = Zt[swz(k0 + j, cw)];
#pragma unroll
        for (int i = 0; i < 4; i++) {
            Frag a;
            a.q = *(const uint4*)(Ab + swz(i * 32 + m, k0));
            acc[i] = __builtin_amdgcn_mfma_f32_32x32x16_bf16(a.v, b.v, acc[i], 0, 0, 0);
        }
    }
    float* og = out + (size_t)(g * NROW) * D + nt * 128 + cw;
#pragma unroll
    for (int i = 0; i < 4; i++)
#pragma unroll
        for (int reg = 0; reg < 16; reg++) {
            int row = i * 32 + (reg & 3) + 8 * (reg >> 2) + 4 * h;
            og[(size_t)row * D] = acc[i][reg] * ss - cs[row];
        }
}

// ------------------------------------------------------------------ launcher
extern "C" void kernel_launch(void* const* d_in, const int* in_sizes, int n_in,
                              void* d_out, int out_size, void* d_ws, size_t ws_size,
                              hipStream_t stream) {
    const float* W = (const float*)d_in[0];
    float* out = (float*)d_out;
    char* ws = (char*)d_ws;

    // ws layout (bytes): Zraw bf16 [2048*9216]       @ 0        (37,748,736)
    //                    Spart f32 [256*16384]       @ 37748736 (16,777,216)
    //                    (unused, was Sred)          @ 54525952 ( 1,048,576)
    //                    gnorm f32 [16]              @ 55574528 (        64)
    //                    Bt bf16 [16*16384]          @ 55575552 (   524,288)
    //                    rowsumPart f32 [16*16*128]  @ 56099840 (   131,072)
    //                    cvec f32 [16*128]           @ 56230912 (     8,192)
    unsigned short* Zraw = (unsigned short*)(ws);
    float* Spart = (float*)(ws + 37748736ULL);
    float* gnorm = (float*)(ws + 55574528ULL);
    unsigned short* Bt = (unsigned short*)(ws + 55575552ULL);
    float* rowsumPart = (float*)(ws + 56099840ULL);
    float* cvec = (float*)(ws + 56230912ULL);

    k_sgemm<<<G * KSPLIT, 256, 0, stream>>>(W, Zraw, Spart, rowsumPart);
    hipFuncSetAttribute((const void*)k_ns,
                        hipFuncAttributeMaxDynamicSharedMemorySize, 131072);
    k_ns<<<G, 512, 131072, stream>>>(Spart, rowsumPart, Bt, cvec, gnorm);
    k_wgemm<<<dim3(72, G), 256, 0, stream>>>(Zraw, Bt, gnorm, cvec, out);
}

// Round 8
// 212.586 us; speedup vs baseline: 1.1486x; 1.1486x over previous
//
#include <hip/hip_runtime.h>

// ONINorm: g=16 groups, n=128 rows/group, d=9216 cols, T=5 Newton-Schulz iters.
// v11 (resubmit #2; R7 was an infra failure with the same signature as R4,
// whose identical resubmit then passed) = v5 verbatim (187.7us best-known:
// k_reduce/k_ns/k_wgemm untouched) except k_sgemm is the v6 8-wave structure
// with the diagnosed defect fixed: __launch_bounds__(512, 2) -- the 2nd arg
// (min waves/EU) raises the VGPR cap to 256/thread. v6's failure was the
// missing arg: cap 128 -> pf[16]+acc spilled to scratch (WRITE +16.6MB,
// Occ 0.6%). With the fix: no spill, 8 waves/CU (vs v5's 4), same bytes,
// same KSPLIT=16, same ws layout. Two wave-sets each own 288 cols
// (128+128+32 steps) in their own 32KB tile; cross-set reduce reuses the
// dead tiles as a 64KB f32 buffer.
//   S = Z*Z^T - d*mu*mu^T ; W = (B5*Z)*ss - (B5*mu)*ss*1^T

#define G 16
#define NROW 128
#define D 9216
#define OC 2048
#define KSPLIT 16
#define KCHUNK 576   // D / KSPLIT; per wave-set: 288 = 128 + 128 + 32
#define SETC 288
#define EPSV 1e-5f

typedef float f32x16 __attribute__((ext_vector_type(16)));
typedef __bf16 bf16x8 __attribute__((ext_vector_type(8)));

union Frag {
    uint4 q;
    unsigned short s[8];
    bf16x8 v;
};

static __device__ __forceinline__ unsigned short f2bf(float x) {
    union { float f; unsigned int u; } a; a.f = x;
    unsigned int u = a.u;
    unsigned int r = u + 0x7FFFu + ((u >> 16) & 1u);   // RNE, inputs are finite
    return (unsigned short)(r >> 16);
}

static __device__ __forceinline__ float bf2f(unsigned short s) {
    union { unsigned int u; float f; } a; a.u = ((unsigned int)s) << 16;
    return a.f;
}

// Swizzled 128x128 bf16 tile layout. Granule = 8 elems = 16B.
// addr(r,c) = r*128 + ((c/8) ^ (r&15))*8 + c%8
static __device__ __forceinline__ int swz(int r, int c) {
    return (r << 7) + ((((c >> 3) ^ (r & 15)) << 3) | (c & 7));
}

// --------------- K1: G partials from raw W + Zraw bf16 byproduct + rowsums ----
// 512 threads = 2 wave-sets, each set = 4 waves with the proven v5 step body.
// Set s covers cols [s*288, s*288+288): steps 128/128/32, own 32KB tile.
// After the last MFMA both tiles are dead -> reused as 64KB f32 buffer for the
// cross-set partial sum, so Spart traffic is identical to v5.
__global__ __launch_bounds__(512, 2) void k_sgemm(const float* __restrict__ W,
                                                  unsigned short* __restrict__ Zraw,
                                                  float* __restrict__ Spart,
                                                  float* __restrict__ rowsumPart) {
    __shared__ unsigned short tile[2][NROW * 128];
    __shared__ float rsum[NROW];
    int bid = blockIdx.x;
    int g = bid >> 4, ks = bid & 15;
    int t = threadIdx.x, lane = t & 63, wave = t >> 6;
    int set = wave >> 2;          // 0: cols [0,288)   1: cols [288,576)
    int ts = t & 255;             // thread index within the set
    int w4 = wave & 3;
    int mq = (w4 & 1) * 64, nq = (w4 >> 1) * 64;
    int m = lane & 31, h = lane >> 5;
    unsigned short* tl = tile[set];

    if (t < 128) rsum[t] = 0.f;

    f32x16 acc[2][2];
#pragma unroll
    for (int i = 0; i < 2; i++)
#pragma unroll
        for (int j = 0; j < 2; j++)
#pragma unroll
            for (int z = 0; z < 16; z++) acc[i][j][z] = 0.f;

    float rs[16], rq[4];
#pragma unroll
    for (int i = 0; i < 16; i++) rs[i] = 0.f;
#pragma unroll
    for (int i = 0; i < 4; i++) rq[i] = 0.f;

    const float* wg = W + (size_t)g * NROW * D + ks * KCHUNK + set * SETC;
    unsigned short* zo = Zraw + (size_t)g * NROW * D + ks * KCHUNK + set * SETC;

    float4 pf[16];
#pragma unroll
    for (int p = 0; p < 16; p++) {                 // preload full step 0
        int fl = p * 256 + ts, r = fl >> 5, cf = fl & 31;
        pf[p] = *(const float4*)(wg + (size_t)r * D + cf * 4);
    }

    for (int step = 0; step < 3; step++) {
        __syncthreads();
        if (step < 2) {                            // full 128-col step
            int dbase = step * 128;
#pragma unroll
            for (int p = 0; p < 16; p++) {
                int fl = p * 256 + ts, r = fl >> 5, cf = fl & 31;
                float4 x = pf[p];
                rs[p] += x.x + x.y + x.z + x.w;
                ushort4 pk;
                pk.x = f2bf(x.x); pk.y = f2bf(x.y);
                pk.z = f2bf(x.z); pk.w = f2bf(x.w);
                *(ushort4*)(zo + (size_t)r * D + dbase + cf * 4) = pk;
                union { ushort4 s4; uint2 u; } cv; cv.s4 = pk;
                *(uint2*)(tl + swz(r, cf * 4)) = cv.u;
            }
        } else {                                   // 32-col tail step
#pragma unroll
            for (int p = 0; p < 4; p++) {
                int fl = p * 256 + ts, r = fl >> 3, cf = fl & 7;
                float4 x = pf[p];
                rq[p] += x.x + x.y + x.z + x.w;
                ushort4 pk;
                pk.x = f2bf(x.x); pk.y = f2bf(x.y);
                pk.z = f2bf(x.z); pk.w = f2bf(x.w);
                *(ushort4*)(zo + (size_t)r * D + 256 + cf * 4) = pk;
                union { ushort4 s4; uint2 u; } cv; cv.s4 = pk;
                *(uint2*)(tl + swz(r, cf * 4)) = cv.u;
            }
        }
        __syncthreads();
        if (step == 0) {                           // prefetch full step 1
#pragma unroll
            for (int p = 0; p < 16; p++) {
                int fl = p * 256 + ts, r = fl >> 5, cf = fl & 31;
                pf[p] = *(const float4*)(wg + (size_t)r * D + 128 + cf * 4);
            }
        } else if (step == 1) {                    // prefetch 32-col tail
#pragma unroll
            for (int p = 0; p < 4; p++) {
                int fl = p * 256 + ts, r = fl >> 3, cf = fl & 7;
                pf[p] = *(const float4*)(wg + (size_t)r * D + 256 + cf * 4);
            }
        }
        int kmax = (step < 2) ? 8 : 2;
#pragma unroll
        for (int kk = 0; kk < 8; kk++) {
            if (kk >= kmax) break;
            int kb = kk * 16 + h * 8;
            Frag a0, a1, b0, b1;
            a0.q = *(const uint4*)(tl + swz(mq + m, kb));
            a1.q = *(const uint4*)(tl + swz(mq + 32 + m, kb));
            b0.q = *(const uint4*)(tl + swz(nq + m, kb));
            b1.q = *(const uint4*)(tl + swz(nq + 32 + m, kb));
            acc[0][0] = __builtin_amdgcn_mfma_f32_32x32x16_bf16(a0.v, b0.v, acc[0][0], 0, 0, 0);
            acc[0][1] = __builtin_amdgcn_mfma_f32_32x32x16_bf16(a0.v, b1.v, acc[0][1], 0, 0, 0);
            acc[1][0] = __builtin_amdgcn_mfma_f32_32x32x16_bf16(a1.v, b0.v, acc[1][0], 0, 0, 0);
            acc[1][1] = __builtin_amdgcn_mfma_f32_32x32x16_bf16(a1.v, b1.v, acc[1][1], 0, 0, 0);
        }
    }
    // fold per-thread rowsums into LDS (covers the block's full 576 cols)
#pragma unroll
    for (int p = 0; p < 16; p++) atomicAdd(&rsum[p * 8 + (ts >> 5)], rs[p]);
#pragma unroll
    for (int p = 0; p < 4; p++) atomicAdd(&rsum[p * 32 + (ts >> 3)], rq[p]);

    __syncthreads();               // all MFMAs + atomics done; tiles now free
    float* Sf = (float*)tile;      // 2 x 32KB tiles = exactly 128*128 f32
    if (set == 0) {
#pragma unroll
        for (int i = 0; i < 2; i++)
#pragma unroll
            for (int j = 0; j < 2; j++)
#pragma unroll
                for (int reg = 0; reg < 16; reg++) {
                    int row = mq + i * 32 + (reg & 3) + 8 * (reg >> 2) + 4 * h;
                    Sf[row * 128 + nq + j * 32 + m] = acc[i][j][reg];
                }
    }
    if (t < 128) rowsumPart[bid * 128 + t] = rsum[t];
    __syncthreads();
    if (set == 1) {
        float* sp = Spart + (size_t)bid * 16384;
#pragma unroll
        for (int i = 0; i < 2; i++)
#pragma unroll
            for (int j = 0; j < 2; j++)
#pragma unroll
                for (int reg = 0; reg < 16; reg++) {
                    int row = mq + i * 32 + (reg & 3) + 8 * (reg >> 2) + 4 * h;
                    int col = nq + j * 32 + m;
                    sp[row * 128 + col] = acc[i][j][reg] + Sf[row * 128 + col];
                }
    }
}

// ------- K2: reduce partials - d*mu*mu^T + eps*I + per-block fro-norm partial --
__global__ __launch_bounds__(256) void k_reduce(const float* __restrict__ Spart,
                                                const float* __restrict__ rowsumPart,
                                                float* __restrict__ Sred,
                                                float* __restrict__ normPart) {
    __shared__ float muv[128];
    __shared__ float ls[4];
    int b = blockIdx.x;
    int g = b >> 4, part = b & 15;
    int t = threadIdx.x;
    if (t < 128) {
        float s = 0.f;
        for (int ks = 0; ks < KSPLIT; ks++) s += rowsumPart[(g * 16 + ks) * 128 + t];
        muv[t] = s * (1.0f / 9216.0f);
    }
    __syncthreads();
    int el = part * 1024 + t * 4;
    float4 s = {0.f, 0.f, 0.f, 0.f};
    for (int ks = 0; ks < KSPLIT; ks++) {
        float4 p = *(const float4*)(Spart + (size_t)(g * KSPLIT + ks) * 16384 + el);
        s.x += p.x; s.y += p.y; s.z += p.z; s.w += p.w;
    }
    int r = el >> 7, c = el & 127;
    float4 mc = *(float4*)&muv[c];
    float dm = 9216.0f * muv[r];
    s.x -= dm * mc.x; s.y -= dm * mc.y; s.z -= dm * mc.z; s.w -= dm * mc.w;
    if (r >= c && r <= c + 3) {
        if (r == c) s.x += EPSV;
        else if (r == c + 1) s.y += EPSV;
        else if (r == c + 2) s.z += EPSV;
        else s.w += EPSV;
    }
    *(float4*)(Sred + (size_t)g * 16384 + el) = s;
    float sq = s.x * s.x + s.y * s.y + s.z * s.z + s.w * s.w;
#pragma unroll
    for (int o = 32; o > 0; o >>= 1) sq += __shfl_down(sq, o, 64);
    if ((t & 63) == 0) ls[t >> 6] = sq;
    __syncthreads();
    if (t == 0) normPart[b] = ls[0] + ls[1] + ls[2] + ls[3];
}

// ------------------------------- K3: Newton-Schulz (one blk/group) + c = B5*mu --
__global__ __launch_bounds__(512) void k_ns(const float* __restrict__ Sred,
                                            const float* __restrict__ normPart,
                                            const float* __restrict__ rowsumPart,
                                            unsigned short* __restrict__ Bt,
                                            float* __restrict__ cvec) {
    extern __shared__ unsigned short sm[];
    unsigned short* Bb = sm;
    unsigned short* Sb = sm + 16384;
    unsigned short* Ub = sm + 32768;
    unsigned short* Vt = sm + 49152;
    int g = blockIdx.x;
    int t = threadIdx.x, lane = t & 63, wave = t >> 6;
    int m = lane & 31, h = lane >> 5;

    float ns = 0.f;
#pragma unroll
    for (int i = 0; i < 16; i++) ns += normPart[g * 16 + i];
    float rn = 1.0f / sqrtf(ns);

    {   // init Sn (bf16) and B1 = 1.5I - 0.5*Sn  (each thread 1/4 row)
        int r = t >> 2, c0 = (t & 3) * 32;
        const float* sp = Sred + (size_t)g * 16384 + r * 128 + c0;
#pragma unroll
        for (int q = 0; q < 4; q++) {
            int c = c0 + q * 8;
            float4 x0 = *(const float4*)(sp + q * 8);
            float4 x1 = *(const float4*)(sp + q * 8 + 4);
            float vv[8] = {x0.x, x0.y, x0.z, x0.w, x1.x, x1.y, x1.z, x1.w};
            Frag fs, fb;
#pragma unroll
            for (int i = 0; i < 8; i++) {
                float sv = vv[i] * rn;
                fs.s[i] = f2bf(sv);
                float bv = -0.5f * sv + ((r == c + i) ? 1.5f : 0.f);
                fb.s[i] = f2bf(bv);
            }
            *(uint4*)(Sb + swz(r, c)) = fs.q;
            *(uint4*)(Bb + swz(r, c)) = fb.q;
        }
    }
    Frag fI[2];   // 1.5*I A-fragments
#pragma unroll
    for (int kk2 = 0; kk2 < 2; kk2++)
#pragma unroll
        for (int j = 0; j < 8; j++)
            fI[kk2].s[j] = (m == kk2 * 16 + h * 8 + j) ? (unsigned short)0x3FC0
                                                       : (unsigned short)0;
    __syncthreads();

    for (int iter = 0; iter < 4; iter++) {
        // phase1: 32 tile-tasks (16 U=B*B^T + 16 V=(-0.5 B*S)^T) over 8 waves
#pragma unroll
        for (int i = 0; i < 4; i++) {
            int task = wave * 4 + i;
            int tmb = ((task >> 2) & 3) * 32, tnb = (task & 3) * 32;
            const unsigned short* Bsrc = (task < 16) ? Bb : Sb;
            unsigned short* dst = (task < 16) ? Ub : Vt;
            float sc = (task < 16) ? 1.0f : -0.5f;
            f32x16 acc;
#pragma unroll
            for (int z = 0; z < 16; z++) acc[z] = 0.f;
#pragma unroll
            for (int kk = 0; kk < 8; kk++) {
                Frag a, bfr;
                a.q = *(const uint4*)(Bb + swz(tmb + m, kk * 16 + h * 8));
                bfr.q = *(const uint4*)(Bsrc + swz(tnb + m, kk * 16 + h * 8));
                acc = __builtin_amdgcn_mfma_f32_32x32x16_bf16(a.v, bfr.v, acc, 0, 0, 0);
            }
#pragma unroll
            for (int q = 0; q < 4; q++) {
                union { unsigned short s[4]; uint2 u; } pk;
#pragma unroll
                for (int j = 0; j < 4; j++) pk.s[j] = f2bf(sc * acc[q * 4 + j]);
                *(uint2*)(dst + swz(tnb + m, tmb + q * 8 + h * 4)) = pk.u;
            }
        }
        __syncthreads();
        // phase2: Bnew = U*V' + 1.5I*B in registers
        f32x16 acc2[2];
#pragma unroll
        for (int i = 0; i < 2; i++) {
            int task = wave * 2 + i;
            int tmb = (task >> 2) * 32, tnb = (task & 3) * 32;
#pragma unroll
            for (int z = 0; z < 16; z++) acc2[i][z] = 0.f;
#pragma unroll
            for (int kk = 0; kk < 8; kk++) {
                Frag a, bfr;
                a.q = *(const uint4*)(Ub + swz(tmb + m, kk * 16 + h * 8));
                bfr.q = *(const uint4*)(Vt + swz(tnb + m, kk * 16 + h * 8));
                acc2[i] = __builtin_amdgcn_mfma_f32_32x32x16_bf16(a.v, bfr.v, acc2[i], 0, 0, 0);
            }
#pragma unroll
            for (int kk2 = 0; kk2 < 2; kk2++) {
                Frag bfr;
                bfr.q = *(const uint4*)(Bb + swz(tnb + m, tmb + kk2 * 16 + h * 8));
                acc2[i] = __builtin_amdgcn_mfma_f32_32x32x16_bf16(fI[kk2].v, bfr.v, acc2[i], 0, 0, 0);
            }
        }
        __syncthreads();
#pragma unroll
        for (int i = 0; i < 2; i++) {
            int task = wave * 2 + i;
            int tmb = (task >> 2) * 32, tnb = (task & 3) * 32;
#pragma unroll
            for (int q = 0; q < 4; q++) {
                union { unsigned short s[4]; uint2 u; } pk;
#pragma unroll
                for (int j = 0; j < 4; j++) pk.s[j] = f2bf(acc2[i][q * 4 + j]);
                *(uint2*)(Bb + swz(tnb + m, tmb + q * 8 + h * 4)) = pk.u;
            }
        }
        __syncthreads();
    }
    {   // write B5 row-major bf16 to global
        int r = t >> 2, c0 = (t & 3) * 32;
        unsigned short* bp = Bt + (size_t)g * 16384 + r * 128;
#pragma unroll
        for (int q = 0; q < 4; q++) {
            uint4 dd = *(const uint4*)(Bb + swz(r, c0 + q * 8));
            *(uint4*)(bp + c0 + q * 8) = dd;
        }
    }
    // c = B5 * mu  (mu from rowsum partials; muv overlays the now-free Ub region)
    float* muv = (float*)(sm + 32768);
    if (t < 128) {
        float s = 0.f;
        for (int ks = 0; ks < KSPLIT; ks++) s += rowsumPart[(g * 16 + ks) * 128 + t];
        muv[t] = s * (1.0f / 9216.0f);
    }
    __syncthreads();
    if (t < 128) {
        float cacc = 0.f;
        for (int k = 0; k < 128; k++) cacc += bf2f(Bb[swz(t, k)]) * muv[k];
        cvec[g * 128 + t] = cacc;
    }
}

// --------------- K4: out = (B5 * Zraw)*ss - (B5*mu)*ss, row-broadcast ---------
__global__ __launch_bounds__(256) void k_wgemm(const unsigned short* __restrict__ Zraw,
                                               const unsigned short* __restrict__ Bt,
                                               const float* __restrict__ normPart,
                                               const float* __restrict__ cvec,
                                               float* __restrict__ out) {
    __shared__ unsigned short Ab[16384];   // B5 tile, swizzled [row][k]
    __shared__ unsigned short Zt[16384];   // Zraw slice, swizzled [k][col]
    __shared__ float cs[128];
    int nt = blockIdx.x, g = blockIdx.y;
    int t = threadIdx.x, lane = t & 63, wave = t >> 6;
    int m = lane & 31, h = lane >> 5;

    float nsum = 0.f;
#pragma unroll
    for (int i = 0; i < 16; i++) nsum += normPart[g * 16 + i];
    float ss = 1.0f / sqrtf(sqrtf(nsum));   // 1/sqrt(norm_S)

    const unsigned short* bg = Bt + (size_t)g * 16384;
    const unsigned short* zg = Zraw + (size_t)g * NROW * D + nt * 128;
#pragma unroll
    for (int p = 0; p < 8; p++) {
        int flat = p * 256 + t;
        int r = flat >> 4, gc = flat & 15;
        uint4 da = *(const uint4*)(bg + r * 128 + gc * 8);
        uint4 dz = *(const uint4*)(zg + (size_t)r * D + gc * 8);
        *(uint4*)(Ab + swz(r, gc * 8)) = da;
        *(uint4*)(Zt + swz(r, gc * 8)) = dz;
    }
    if (t < 128) cs[t] = cvec[g * 128 + t] * ss;
    __syncthreads();

    int cw = wave * 32 + m;                  // this lane's output column (in tile)

    f32x16 acc[4];
#pragma unroll
    for (int i = 0; i < 4; i++)
#pragma unroll
        for (int z = 0; z < 16; z++) acc[i][z] = 0.f;

#pragma unroll
    for (int ks = 0; ks < 8; ks++) {
        int k0 = ks * 16 + h * 8;
        Frag b;
#pragma unroll
        for (int j = 0; j < 8; j++) b.s[j] = Zt[swz(k0 + j, cw)];
#pragma unroll
        for (int i = 0; i < 4; i++) {
            Frag a;
            a.q = *(const uint4*)(Ab + swz(i * 32 + m, k0));
            acc[i] = __builtin_amdgcn_mfma_f32_32x32x16_bf16(a.v, b.v, acc[i], 0, 0, 0);
        }
    }
    float* og = out + (size_t)(g * NROW) * D + nt * 128 + cw;
#pragma unroll
    for (int i = 0; i < 4; i++)
#pragma unroll
        for (int reg = 0; reg < 16; reg++) {
            int row = i * 32 + (reg & 3) + 8 * (reg >> 2) + 4 * h;
            og[(size_t)row * D] = acc[i][reg] * ss - cs[row];
        }
}

// ------------------------------------------------------------------ launcher
extern "C" void kernel_launch(void* const* d_in, const int* in_sizes, int n_in,
                              void* d_out, int out_size, void* d_ws, size_t ws_size,
                              hipStream_t stream) {
    const float* W = (const float*)d_in[0];
    float* out = (float*)d_out;
    char* ws = (char*)d_ws;

    // ws layout (bytes): Zraw bf16 [2048*9216]       @ 0        (37,748,736)
    //                    Spart f32 [256*16384]       @ 37748736 (16,777,216)
    //                    Sred f32 [16*16384]         @ 54525952 ( 1,048,576)
    //                    normPart f32 [256]          @ 55574528 (     1,024)
    //                    Bt bf16 [16*16384]          @ 55575552 (   524,288)
    //                    rowsumPart f32 [16*16*128]  @ 56099840 (   131,072)
    //                    cvec f32 [16*128]           @ 56230912 (     8,192)
    unsigned short* Zraw = (unsigned short*)(ws);
    float* Spart = (float*)(ws + 37748736ULL);
    float* Sred = (float*)(ws + 54525952ULL);
    float* normPart = (float*)(ws + 55574528ULL);
    unsigned short* Bt = (unsigned short*)(ws + 55575552ULL);
    float* rowsumPart = (float*)(ws + 56099840ULL);
    float* cvec = (float*)(ws + 56230912ULL);

    k_sgemm<<<G * KSPLIT, 512, 0, stream>>>(W, Zraw, Spart, rowsumPart);
    k_reduce<<<256, 256, 0, stream>>>(Spart, rowsumPart, Sred, normPart);
    hipFuncSetAttribute((const void*)k_ns,
                        hipFuncAttributeMaxDynamicSharedMemorySize, 131072);
    k_ns<<<G, 512, 131072, stream>>>(Sred, normPart, rowsumPart, Bt, cvec);
    k_wgemm<<<dim3(72, G), 256, 0, stream>>>(Zraw, Bt, normPart, cvec, out);
}

// Round 9
// 185.277 us; speedup vs baseline: 1.3179x; 1.1474x over previous
//
#include <hip/hip_runtime.h>

// ONINorm: g=16 groups, n=128 rows/group, d=9216 cols, T=5 Newton-Schulz iters.
// v12 = v5 verbatim (187.7us best-known; k_reduce/k_ns/k_wgemm untouched)
// except k_sgemm's __syncthreads() are replaced by lgkm-only barriers:
//   s_waitcnt lgkmcnt(0) + s_barrier + sched_barrier(0)
// __syncthreads drains vmcnt(0) too, which (a) stalled every barrier on the
// Zraw global stores (never read in-kernel) and (b) coupled all 4 waves to the
// slowest wave's prefetch loads 10x per block. LDS ordering (the only real
// cross-wave hazard: tile writes -> MFMA reads -> tile overwrite) is fully
// preserved by lgkmcnt(0). Prefetch loads are consumed same-wave (compiler
// inserts counted vmcnt); Zraw/Spart stores drain at kernel end.
// v6/v7/v11 closed the "more waves" family: 8-wave blocks always split the
// unified file 128+128 -> spill; K1's 160-VGPR 4-wave body is final.
//   S = Z*Z^T - d*mu*mu^T ; W = (B5*Z)*ss - (B5*mu)*ss*1^T

#define G 16
#define NROW 128
#define D 9216
#define OC 2048
#define KSPLIT 16
#define KCHUNK 576   // D / KSPLIT = 4*128 + 64
#define EPSV 1e-5f

typedef float f32x16 __attribute__((ext_vector_type(16)));
typedef __bf16 bf16x8 __attribute__((ext_vector_type(8)));

union Frag {
    uint4 q;
    unsigned short s[8];
    bf16x8 v;
};

static __device__ __forceinline__ unsigned short f2bf(float x) {
    union { float f; unsigned int u; } a; a.f = x;
    unsigned int u = a.u;
    unsigned int r = u + 0x7FFFu + ((u >> 16) & 1u);   // RNE, inputs are finite
    return (unsigned short)(r >> 16);
}

static __device__ __forceinline__ float bf2f(unsigned short s) {
    union { unsigned int u; float f; } a; a.u = ((unsigned int)s) << 16;
    return a.f;
}

// Barrier that orders LDS ops only (does NOT drain vmcnt like __syncthreads).
static __device__ __forceinline__ void lgkm_barrier() {
    asm volatile("s_waitcnt lgkmcnt(0)" ::: "memory");
    __builtin_amdgcn_s_barrier();
    __builtin_amdgcn_sched_barrier(0);   // rule-18 fence: no hoisting across
}

// Swizzled 128x128 bf16 tile layout. Granule = 8 elems = 16B.
// addr(r,c) = r*128 + ((c/8) ^ (r&15))*8 + c%8
static __device__ __forceinline__ int swz(int r, int c) {
    return (r << 7) + ((((c >> 3) ^ (r & 15)) << 3) | (c & 7));
}

// --------------- K1: G partials from raw W + Zraw bf16 byproduct + rowsums ----
// v5 structure (256 thr, 160 VGPR, 5 steps of 128/128/128/128/64 cols);
// only the barrier semantics changed (lgkm-only).
__global__ __launch_bounds__(256) void k_sgemm(const float* __restrict__ W,
                                               unsigned short* __restrict__ Zraw,
                                               float* __restrict__ Spart,
                                               float* __restrict__ rowsumPart) {
    __shared__ unsigned short tile[NROW * 128];
    __shared__ float rsum[NROW];
    int bid = blockIdx.x;
    int g = bid >> 4, ks = bid & 15;
    int t = threadIdx.x, lane = t & 63, wave = t >> 6;
    int mq = (wave & 1) * 64, nq = (wave >> 1) * 64;
    int m = lane & 31, h = lane >> 5;

    if (t < 128) rsum[t] = 0.f;

    f32x16 acc[2][2];
#pragma unroll
    for (int i = 0; i < 2; i++)
#pragma unroll
        for (int j = 0; j < 2; j++)
#pragma unroll
            for (int z = 0; z < 16; z++) acc[i][j][z] = 0.f;

    float rs[16], rsh[8];
#pragma unroll
    for (int i = 0; i < 16; i++) rs[i] = 0.f;
#pragma unroll
    for (int i = 0; i < 8; i++) rsh[i] = 0.f;

    const float* wg = W + (size_t)g * NROW * D + ks * KCHUNK;
    unsigned short* zo = Zraw + (size_t)g * NROW * D + ks * KCHUNK;

    float4 pf[16];
#pragma unroll
    for (int p = 0; p < 16; p++) {                 // preload full step 0
        int fl = p * 256 + t, r = fl >> 5, cf = fl & 31;
        pf[p] = *(const float4*)(wg + (size_t)r * D + cf * 4);
    }

    for (int step = 0; step < 5; step++) {
        lgkm_barrier();                            // tile free (prev MFMA done)
        if (step < 4) {
            int dbase = step * 128;
#pragma unroll
            for (int p = 0; p < 16; p++) {
                int fl = p * 256 + t, r = fl >> 5, cf = fl & 31;
                float4 x = pf[p];
                rs[p] += x.x + x.y + x.z + x.w;
                ushort4 pk;
                pk.x = f2bf(x.x); pk.y = f2bf(x.y);
                pk.z = f2bf(x.z); pk.w = f2bf(x.w);
                *(ushort4*)(zo + (size_t)r * D + dbase + cf * 4) = pk;
                union { ushort4 s4; uint2 u; } cv; cv.s4 = pk;
                *(uint2*)(tile + swz(r, cf * 4)) = cv.u;
            }
        } else {
#pragma unroll
            for (int p = 0; p < 8; p++) {
                int fl = p * 256 + t, r = fl >> 4, cf = fl & 15;
                float4 x = pf[p];
                rsh[p] += x.x + x.y + x.z + x.w;
                ushort4 pk;
                pk.x = f2bf(x.x); pk.y = f2bf(x.y);
                pk.z = f2bf(x.z); pk.w = f2bf(x.w);
                *(ushort4*)(zo + (size_t)r * D + 512 + cf * 4) = pk;
                union { ushort4 s4; uint2 u; } cv; cv.s4 = pk;
                *(uint2*)(tile + swz(r, cf * 4)) = cv.u;
            }
        }
        lgkm_barrier();                            // tile filled, MFMA may read
        if (step < 3) {                            // prefetch next full step
            int dbase = (step + 1) * 128;
#pragma unroll
            for (int p = 0; p < 16; p++) {
                int fl = p * 256 + t, r = fl >> 5, cf = fl & 31;
                pf[p] = *(const float4*)(wg + (size_t)r * D + dbase + cf * 4);
            }
        } else if (step == 3) {                    // prefetch half step
#pragma unroll
            for (int p = 0; p < 8; p++) {
                int fl = p * 256 + t, r = fl >> 4, cf = fl & 15;
                pf[p] = *(const float4*)(wg + (size_t)r * D + 512 + cf * 4);
            }
        }
        int kmax = (step < 4) ? 8 : 4;
#pragma unroll
        for (int kk = 0; kk < 8; kk++) {
            if (kk >= kmax) break;
            int kb = kk * 16 + h * 8;
            Frag a0, a1, b0, b1;
            a0.q = *(const uint4*)(tile + swz(mq + m, kb));
            a1.q = *(const uint4*)(tile + swz(mq + 32 + m, kb));
            b0.q = *(const uint4*)(tile + swz(nq + m, kb));
            b1.q = *(const uint4*)(tile + swz(nq + 32 + m, kb));
            acc[0][0] = __builtin_amdgcn_mfma_f32_32x32x16_bf16(a0.v, b0.v, acc[0][0], 0, 0, 0);
            acc[0][1] = __builtin_amdgcn_mfma_f32_32x32x16_bf16(a0.v, b1.v, acc[0][1], 0, 0, 0);
            acc[1][0] = __builtin_amdgcn_mfma_f32_32x32x16_bf16(a1.v, b0.v, acc[1][0], 0, 0, 0);
            acc[1][1] = __builtin_amdgcn_mfma_f32_32x32x16_bf16(a1.v, b1.v, acc[1][1], 0, 0, 0);
        }
    }
    float* sp = Spart + (size_t)bid * 16384;
#pragma unroll
    for (int i = 0; i < 2; i++)
#pragma unroll
        for (int j = 0; j < 2; j++)
#pragma unroll
            for (int reg = 0; reg < 16; reg++) {
                int row = (reg & 3) + 8 * (reg >> 2) + 4 * h;
                sp[(mq + i * 32 + row) * 128 + nq + j * 32 + m] = acc[i][j][reg];
            }
    // fold per-thread rowsums into LDS, then one global write
#pragma unroll
    for (int p = 0; p < 16; p++) atomicAdd(&rsum[p * 8 + (t >> 5)], rs[p]);
#pragma unroll
    for (int p = 0; p < 8; p++) atomicAdd(&rsum[p * 16 + (t >> 4)], rsh[p]);
    lgkm_barrier();                                // LDS atomics ordered
    if (t < 128) rowsumPart[bid * 128 + t] = rsum[t];
}

// ------- K2: reduce partials - d*mu*mu^T + eps*I + per-block fro-norm partial --
__global__ __launch_bounds__(256) void k_reduce(const float* __restrict__ Spart,
                                                const float* __restrict__ rowsumPart,
                                                float* __restrict__ Sred,
                                                float* __restrict__ normPart) {
    __shared__ float muv[128];
    __shared__ float ls[4];
    int b = blockIdx.x;
    int g = b >> 4, part = b & 15;
    int t = threadIdx.x;
    if (t < 128) {
        float s = 0.f;
        for (int ks = 0; ks < KSPLIT; ks++) s += rowsumPart[(g * 16 + ks) * 128 + t];
        muv[t] = s * (1.0f / 9216.0f);
    }
    __syncthreads();
    int el = part * 1024 + t * 4;
    float4 s = {0.f, 0.f, 0.f, 0.f};
    for (int ks = 0; ks < KSPLIT; ks++) {
        float4 p = *(const float4*)(Spart + (size_t)(g * KSPLIT + ks) * 16384 + el);
        s.x += p.x; s.y += p.y; s.z += p.z; s.w += p.w;
    }
    int r = el >> 7, c = el & 127;
    float4 mc = *(float4*)&muv[c];
    float dm = 9216.0f * muv[r];
    s.x -= dm * mc.x; s.y -= dm * mc.y; s.z -= dm * mc.z; s.w -= dm * mc.w;
    if (r >= c && r <= c + 3) {
        if (r == c) s.x += EPSV;
        else if (r == c + 1) s.y += EPSV;
        else if (r == c + 2) s.z += EPSV;
        else s.w += EPSV;
    }
    *(float4*)(Sred + (size_t)g * 16384 + el) = s;
    float sq = s.x * s.x + s.y * s.y + s.z * s.z + s.w * s.w;
#pragma unroll
    for (int o = 32; o > 0; o >>= 1) sq += __shfl_down(sq, o, 64);
    if ((t & 63) == 0) ls[t >> 6] = sq;
    __syncthreads();
    if (t == 0) normPart[b] = ls[0] + ls[1] + ls[2] + ls[3];
}

// ------------------------------- K3: Newton-Schulz (one blk/group) + c = B5*mu --
__global__ __launch_bounds__(512) void k_ns(const float* __restrict__ Sred,
                                            const float* __restrict__ normPart,
                                            const float* __restrict__ rowsumPart,
                                            unsigned short* __restrict__ Bt,
                                            float* __restrict__ cvec) {
    extern __shared__ unsigned short sm[];
    unsigned short* Bb = sm;
    unsigned short* Sb = sm + 16384;
    unsigned short* Ub = sm + 32768;
    unsigned short* Vt = sm + 49152;
    int g = blockIdx.x;
    int t = threadIdx.x, lane = t & 63, wave = t >> 6;
    int m = lane & 31, h = lane >> 5;

    float ns = 0.f;
#pragma unroll
    for (int i = 0; i < 16; i++) ns += normPart[g * 16 + i];
    float rn = 1.0f / sqrtf(ns);

    {   // init Sn (bf16) and B1 = 1.5I - 0.5*Sn  (each thread 1/4 row)
        int r = t >> 2, c0 = (t & 3) * 32;
        const float* sp = Sred + (size_t)g * 16384 + r * 128 + c0;
#pragma unroll
        for (int q = 0; q < 4; q++) {
            int c = c0 + q * 8;
            float4 x0 = *(const float4*)(sp + q * 8);
            float4 x1 = *(const float4*)(sp + q * 8 + 4);
            float vv[8] = {x0.x, x0.y, x0.z, x0.w, x1.x, x1.y, x1.z, x1.w};
            Frag fs, fb;
#pragma unroll
            for (int i = 0; i < 8; i++) {
                float sv = vv[i] * rn;
                fs.s[i] = f2bf(sv);
                float bv = -0.5f * sv + ((r == c + i) ? 1.5f : 0.f);
                fb.s[i] = f2bf(bv);
            }
            *(uint4*)(Sb + swz(r, c)) = fs.q;
            *(uint4*)(Bb + swz(r, c)) = fb.q;
        }
    }
    Frag fI[2];   // 1.5*I A-fragments
#pragma unroll
    for (int kk2 = 0; kk2 < 2; kk2++)
#pragma unroll
        for (int j = 0; j < 8; j++)
            fI[kk2].s[j] = (m == kk2 * 16 + h * 8 + j) ? (unsigned short)0x3FC0
                                                       : (unsigned short)0;
    __syncthreads();

    for (int iter = 0; iter < 4; iter++) {
        // phase1: 32 tile-tasks (16 U=B*B^T + 16 V=(-0.5 B*S)^T) over 8 waves
#pragma unroll
        for (int i = 0; i < 4; i++) {
            int task = wave * 4 + i;
            int tmb = ((task >> 2) & 3) * 32, tnb = (task & 3) * 32;
            const unsigned short* Bsrc = (task < 16) ? Bb : Sb;
            unsigned short* dst = (task < 16) ? Ub : Vt;
            float sc = (task < 16) ? 1.0f : -0.5f;
            f32x16 acc;
#pragma unroll
            for (int z = 0; z < 16; z++) acc[z] = 0.f;
#pragma unroll
            for (int kk = 0; kk < 8; kk++) {
                Frag a, bfr;
                a.q = *(const uint4*)(Bb + swz(tmb + m, kk * 16 + h * 8));
                bfr.q = *(const uint4*)(Bsrc + swz(tnb + m, kk * 16 + h * 8));
                acc = __builtin_amdgcn_mfma_f32_32x32x16_bf16(a.v, bfr.v, acc, 0, 0, 0);
            }
#pragma unroll
            for (int q = 0; q < 4; q++) {
                union { unsigned short s[4]; uint2 u; } pk;
#pragma unroll
                for (int j = 0; j < 4; j++) pk.s[j] = f2bf(sc * acc[q * 4 + j]);
                *(uint2*)(dst + swz(tnb + m, tmb + q * 8 + h * 4)) = pk.u;
            }
        }
        __syncthreads();
        // phase2: Bnew = U*V' + 1.5I*B in registers
        f32x16 acc2[2];
#pragma unroll
        for (int i = 0; i < 2; i++) {
            int task = wave * 2 + i;
            int tmb = (task >> 2) * 32, tnb = (task & 3) * 32;
#pragma unroll
            for (int z = 0; z < 16; z++) acc2[i][z] = 0.f;
#pragma unroll
            for (int kk = 0; kk < 8; kk++) {
                Frag a, bfr;
                a.q = *(const uint4*)(Ub + swz(tmb + m, kk * 16 + h * 8));
                bfr.q = *(const uint4*)(Vt + swz(tnb + m, kk * 16 + h * 8));
                acc2[i] = __builtin_amdgcn_mfma_f32_32x32x16_bf16(a.v, bfr.v, acc2[i], 0, 0, 0);
            }
#pragma unroll
            for (int kk2 = 0; kk2 < 2; kk2++) {
                Frag bfr;
                bfr.q = *(const uint4*)(Bb + swz(tnb + m, tmb + kk2 * 16 + h * 8));
                acc2[i] = __builtin_amdgcn_mfma_f32_32x32x16_bf16(fI[kk2].v, bfr.v, acc2[i], 0, 0, 0);
            }
        }
        __syncthreads();
#pragma unroll
        for (int i = 0; i < 2; i++) {
            int task = wave * 2 + i;
            int tmb = (task >> 2) * 32, tnb = (task & 3) * 32;
#pragma unroll
            for (int q = 0; q < 4; q++) {
                union { unsigned short s[4]; uint2 u; } pk;
#pragma unroll
                for (int j = 0; j < 4; j++) pk.s[j] = f2bf(acc2[i][q * 4 + j]);
                *(uint2*)(Bb + swz(tnb + m, tmb + q * 8 + h * 4)) = pk.u;
            }
        }
        __syncthreads();
    }
    {   // write B5 row-major bf16 to global
        int r = t >> 2, c0 = (t & 3) * 32;
        unsigned short* bp = Bt + (size_t)g * 16384 + r * 128;
#pragma unroll
        for (int q = 0; q < 4; q++) {
            uint4 dd = *(const uint4*)(Bb + swz(r, c0 + q * 8));
            *(uint4*)(bp + c0 + q * 8) = dd;
        }
    }
    // c = B5 * mu  (mu from rowsum partials; muv overlays the now-free Ub region)
    float* muv = (float*)(sm + 32768);
    if (t < 128) {
        float s = 0.f;
        for (int ks = 0; ks < KSPLIT; ks++) s += rowsumPart[(g * 16 + ks) * 128 + t];
        muv[t] = s * (1.0f / 9216.0f);
    }
    __syncthreads();
    if (t < 128) {
        float cacc = 0.f;
        for (int k = 0; k < 128; k++) cacc += bf2f(Bb[swz(t, k)]) * muv[k];
        cvec[g * 128 + t] = cacc;
    }
}

// --------------- K4: out = (B5 * Zraw)*ss - (B5*mu)*ss, row-broadcast ---------
__global__ __launch_bounds__(256) void k_wgemm(const unsigned short* __restrict__ Zraw,
                                               const unsigned short* __restrict__ Bt,
                                               const float* __restrict__ normPart,
                                               const float* __restrict__ cvec,
                                               float* __restrict__ out) {
    __shared__ unsigned short Ab[16384];   // B5 tile, swizzled [row][k]
    __shared__ unsigned short Zt[16384];   // Zraw slice, swizzled [k][col]
    __shared__ float cs[128];
    int nt = blockIdx.x, g = blockIdx.y;
    int t = threadIdx.x, lane = t & 63, wave = t >> 6;
    int m = lane & 31, h = lane >> 5;

    float nsum = 0.f;
#pragma unroll
    for (int i = 0; i < 16; i++) nsum += normPart[g * 16 + i];
    float ss = 1.0f / sqrtf(sqrtf(nsum));   // 1/sqrt(norm_S)

    const unsigned short* bg = Bt + (size_t)g * 16384;
    const unsigned short* zg = Zraw + (size_t)g * NROW * D + nt * 128;
#pragma unroll
    for (int p = 0; p < 8; p++) {
        int flat = p * 256 + t;
        int r = flat >> 4, gc = flat & 15;
        uint4 da = *(const uint4*)(bg + r * 128 + gc * 8);
        uint4 dz = *(const uint4*)(zg + (size_t)r * D + gc * 8);
        *(uint4*)(Ab + swz(r, gc * 8)) = da;
        *(uint4*)(Zt + swz(r, gc * 8)) = dz;
    }
    if (t < 128) cs[t] = cvec[g * 128 + t] * ss;
    __syncthreads();

    int cw = wave * 32 + m;                  // this lane's output column (in tile)

    f32x16 acc[4];
#pragma unroll
    for (int i = 0; i < 4; i++)
#pragma unroll
        for (int z = 0; z < 16; z++) acc[i][z] = 0.f;

#pragma unroll
    for (int ks = 0; ks < 8; ks++) {
        int k0 = ks * 16 + h * 8;
        Frag b;
#pragma unroll
        for (int j = 0; j < 8; j++) b.s[j] = Zt[swz(k0 + j, cw)];
#pragma unroll
        for (int i = 0; i < 4; i++) {
            Frag a;
            a.q = *(const uint4*)(Ab + swz(i * 32 + m, k0));
            acc[i] = __builtin_amdgcn_mfma_f32_32x32x16_bf16(a.v, b.v, acc[i], 0, 0, 0);
        }
    }
    float* og = out + (size_t)(g * NROW) * D + nt * 128 + cw;
#pragma unroll
    for (int i = 0; i < 4; i++)
#pragma unroll
        for (int reg = 0; reg < 16; reg++) {
            int row = i * 32 + (reg & 3) + 8 * (reg >> 2) + 4 * h;
            og[(size_t)row * D] = acc[i][reg] * ss - cs[row];
        }
}

// ------------------------------------------------------------------ launcher
extern "C" void kernel_launch(void* const* d_in, const int* in_sizes, int n_in,
                              void* d_out, int out_size, void* d_ws, size_t ws_size,
                              hipStream_t stream) {
    const float* W = (const float*)d_in[0];
    float* out = (float*)d_out;
    char* ws = (char*)d_ws;

    // ws layout (bytes): Zraw bf16 [2048*9216]       @ 0        (37,748,736)
    //                    Spart f32 [256*16384]       @ 37748736 (16,777,216)
    //                    Sred f32 [16*16384]         @ 54525952 ( 1,048,576)
    //                    normPart f32 [256]          @ 55574528 (     1,024)
    //                    Bt bf16 [16*16384]          @ 55575552 (   524,288)
    //                    rowsumPart f32 [16*16*128]  @ 56099840 (   131,072)
    //                    cvec f32 [16*128]           @ 56230912 (     8,192)
    unsigned short* Zraw = (unsigned short*)(ws);
    float* Spart = (float*)(ws + 37748736ULL);
    float* Sred = (float*)(ws + 54525952ULL);
    float* normPart = (float*)(ws + 55574528ULL);
    unsigned short* Bt = (unsigned short*)(ws + 55575552ULL);
    float* rowsumPart = (float*)(ws + 56099840ULL);
    float* cvec = (float*)(ws + 56230912ULL);

    k_sgemm<<<G * KSPLIT, 256, 0, stream>>>(W, Zraw, Spart, rowsumPart);
    k_reduce<<<256, 256, 0, stream>>>(Spart, rowsumPart, Sred, normPart);
    hipFuncSetAttribute((const void*)k_ns,
                        hipFuncAttributeMaxDynamicSharedMemorySize, 131072);
    k_ns<<<G, 512, 131072, stream>>>(Sred, normPart, rowsumPart, Bt, cvec);
    k_wgemm<<<dim3(72, G), 256, 0, stream>>>(Zraw, Bt, normPart, cvec, out);
}